// Round 1
// baseline (1378.951 us; speedup 1.0000x reference)
//
#include <hip/hip_runtime.h>
#include <stdint.h>

typedef unsigned long long u64;
typedef unsigned int u32;

#define NIMG 16
#define NC 80
#define HW 25600
#define CHW (NC * HW)          // 2,048,000
#define PREK 1000
#define POSTK 200
#define HBINS 8192
#define CAPSEL 8192
#define LOGIT_T (-2.9444389791664403f)   // ln(0.05/0.95)
#define SFLOOR 0.05f
#define CLIPDWH 4.135166556742356f        // ln(1000/16)
#define IMGM1 1279.0f
#define OFFMUL 1281.0f
#define NMSTHR 0.8f

// ---- shared candidate evaluation -------------------------------------------
__device__ __forceinline__ bool cand_score(float l, const float* __restrict__ ctrRow,
                                           int e, float& s) {
  if (!(l > LOGIT_T)) return false;             // prob <= 0.05 -> not a candidate
  int loc = e % HW;
  float p  = 1.0f / (1.0f + expf(-l));
  float g  = ctrRow[loc];
  float cg = 1.0f / (1.0f + expf(-g));
  s = p * cg;
  return true;
}

// ---- K1: per-image histogram of candidate scores ---------------------------
__global__ void k_hist(const float* __restrict__ cls, const float* __restrict__ ctr,
                       int* __restrict__ hist) {
  const int n = blockIdx.y;
  const int e0 = (blockIdx.x * blockDim.x + threadIdx.x) * 4;
  const float4 v = *reinterpret_cast<const float4*>(cls + (size_t)n * CHW + e0);
  const float L[4] = {v.x, v.y, v.z, v.w};
  const float* ctrRow = ctr + (size_t)n * HW;
#pragma unroll
  for (int u = 0; u < 4; ++u) {
    float s;
    if (cand_score(L[u], ctrRow, e0 + u, s)) {
      if (s > SFLOOR) {
        u32 key = __float_as_uint(s) >> 17;     // < 8128
        atomicAdd(&hist[n * HBINS + key], 1);
      }
    }
  }
}

// ---- K2: find cutoff bin B per image (suffix-scan of histogram) ------------
__global__ void k_findB(const int* __restrict__ hist, int* __restrict__ gB,
                        int* __restrict__ gnc) {
  __shared__ int ss[256];
  const int n = blockIdx.x, t = threadIdx.x;
  const int* h = hist + n * HBINS;
  int s = 0;
#pragma unroll 4
  for (int b = 0; b < 32; ++b) s += h[t * 32 + b];
  ss[t] = s;
  __syncthreads();
  for (int off = 1; off < 256; off <<= 1) {     // inclusive suffix scan
    int a = (t + off < 256) ? ss[t + off] : 0;
    __syncthreads();
    ss[t] += a;
    __syncthreads();
  }
  int total = ss[0];
  int ncand = total < PREK ? total : PREK;
  if (t == 0) gnc[n] = ncand;
  if (total == 0) { if (t == 0) gB[n] = HBINS; return; }   // select nothing
  int Sn = (t < 255) ? ss[t + 1] : 0;
  if (ss[t] >= ncand && Sn < ncand) {           // unique boundary chunk
    int run = Sn, B = t * 32;
    for (int b = t * 32 + 31; b >= t * 32; --b) {
      run += h[b];
      if (run >= ncand) { B = b; break; }
    }
    gB[n] = B;
  }
}

// ---- K3: collect candidates with bin >= B ----------------------------------
__global__ void k_collect(const float* __restrict__ cls, const float* __restrict__ ctr,
                          const int* __restrict__ gB, int* __restrict__ selcnt,
                          u64* __restrict__ sel) {
  const int n = blockIdx.y;
  const u32 B = (u32)gB[n];
  const int e0 = (blockIdx.x * blockDim.x + threadIdx.x) * 4;
  const float4 v = *reinterpret_cast<const float4*>(cls + (size_t)n * CHW + e0);
  const float L[4] = {v.x, v.y, v.z, v.w};
  const float* ctrRow = ctr + (size_t)n * HW;
#pragma unroll
  for (int u = 0; u < 4; ++u) {
    float s;
    if (cand_score(L[u], ctrRow, e0 + u, s)) {
      if ((__float_as_uint(s) >> 17) >= B) {
        int e = e0 + u;
        int loc = e % HW, c = e / HW;
        u32 idx = (u32)(loc * NC + c);          // reference flat index [HW, C]
        u64 pk = ((u64)__float_as_uint(s) << 32) | (u32)(~idx);
        int pos = atomicAdd(&selcnt[n], 1);
        if (pos < CAPSEL) sel[(size_t)n * CAPSEL + pos] = pk;
      }
    }
  }
}

// ---- K4: per-image bitonic sort (descending) of selected candidates --------
__global__ __launch_bounds__(1024) void k_sort(const int* __restrict__ selcnt,
                                               const u64* __restrict__ sel,
                                               u64* __restrict__ top) {
  __shared__ u64 a[CAPSEL];                      // 64 KiB
  const int n = blockIdx.x, t = threadIdx.x;
  int cnt = selcnt[n]; if (cnt > CAPSEL) cnt = CAPSEL;
  for (int i = t; i < CAPSEL; i += 1024)
    a[i] = (i < cnt) ? sel[(size_t)n * CAPSEL + i] : 0ULL;
  __syncthreads();
  for (int k = 2; k <= CAPSEL; k <<= 1)
    for (int j = k >> 1; j > 0; j >>= 1) {
      for (int i = t; i < CAPSEL; i += 1024) {
        int ix = i ^ j;
        if (ix > i) {
          u64 x = a[i], y = a[ix];
          bool desc = ((i & k) == 0);
          if (desc ? (x < y) : (x > y)) { a[i] = y; a[ix] = x; }
        }
      }
      __syncthreads();
    }
  top[(size_t)n * 1024 + t] = a[t];
}

// ---- K5: decode boxes, det-scores, offset boxes ----------------------------
__global__ void k_decode(const u64* __restrict__ top, const int* __restrict__ gnc,
                         const float* __restrict__ reg, const float* __restrict__ anch,
                         float4* __restrict__ boxes, float4* __restrict__ nb,
                         float* __restrict__ dsc) {
  const int n = blockIdx.x, k = threadIdx.x;
  if (k >= PREK) return;
  u64 pk = top[(size_t)n * 1024 + k];
  int ncand = gnc[n];
  float4 bx = {0, 0, 0, 0}, nbv = {0, 0, 0, 0};
  float d = 0.0f;
  if (k < ncand && pk != 0ULL) {
    float s = __uint_as_float((u32)(pk >> 32));
    u32 idx = ~(u32)pk;
    int loc = idx / NC, c = idx - loc * NC;
    float r0 = reg[((size_t)n * 4 + 0) * HW + loc];
    float r1 = reg[((size_t)n * 4 + 1) * HW + loc];
    float r2 = reg[((size_t)n * 4 + 2) * HW + loc];
    float r3 = reg[((size_t)n * 4 + 3) * HW + loc];
    float a0 = anch[loc * 4 + 0], a1 = anch[loc * 4 + 1];
    float a2 = anch[loc * 4 + 2], a3 = anch[loc * 4 + 3];
    float w = a2 - a0 + 1.0f, h = a3 - a1 + 1.0f;
    float cx = a0 + 0.5f * w, cy = a1 + 0.5f * h;
    float dx = r0 / 10.0f, dy = r1 / 10.0f;
    float dw = fminf(r2 / 5.0f, CLIPDWH), dh = fminf(r3 / 5.0f, CLIPDWH);
    float pcx = dx * w + cx, pcy = dy * h + cy;
    float pw = expf(dw) * w, ph = expf(dh) * h;
    float x1 = pcx - 0.5f * pw, y1 = pcy - 0.5f * ph;
    float x2 = pcx + 0.5f * pw - 1.0f, y2 = pcy + 0.5f * ph - 1.0f;
    x1 = fminf(fmaxf(x1, 0.0f), IMGM1); y1 = fminf(fmaxf(y1, 0.0f), IMGM1);
    x2 = fminf(fmaxf(x2, 0.0f), IMGM1); y2 = fminf(fmaxf(y2, 0.0f), IMGM1);
    float wsz = x2 - x1 + 1.0f, hsz = y2 - y1 + 1.0f;
    if (wsz >= 0.0f && hsz >= 0.0f) d = sqrtf(s);
    bx = {x1, y1, x2, y2};
    float off = (float)(c + 1) * OFFMUL;        // reference adds offset AFTER clip
    nbv = {x1 + off, y1 + off, x2 + off, y2 + off};
  }
  boxes[n * PREK + k] = bx;
  nb[n * PREK + k] = nbv;
  dsc[n * PREK + k] = d;
}

// ---- K6: suppression bitmask matrix ----------------------------------------
__global__ void k_sup(const float4* __restrict__ nb, const float* __restrict__ dsc,
                      u64* __restrict__ sup) {
  const int i = blockIdx.x, n = blockIdx.y;
  if (dsc[n * PREK + i] == 0.0f) return;        // row never read in greedy phase
  const float4 bi = nb[n * PREK + i];
  const float a1 = fmaxf(bi.z - bi.x, 0.0f) * fmaxf(bi.w - bi.y, 0.0f);
  const int tid = threadIdx.x, lane = tid & 63, wv = tid >> 6;
#pragma unroll
  for (int rep = 0; rep < 4; ++rep) {
    int j = rep * 256 + tid;
    bool bit = false;
    if (j < PREK && j > i) {
      float4 bj = nb[n * PREK + j];
      float xx1 = fmaxf(bi.x, bj.x), yy1 = fmaxf(bi.y, bj.y);
      float xx2 = fminf(bi.z, bj.z), yy2 = fminf(bi.w, bj.w);
      float inter = fmaxf(xx2 - xx1, 0.0f) * fmaxf(yy2 - yy1, 0.0f);
      float a2 = fmaxf(bj.z - bj.x, 0.0f) * fmaxf(bj.w - bj.y, 0.0f);
      float iou = inter / fmaxf(a1 + a2 - inter, 1e-9f);
      bit = iou > NMSTHR;
    }
    u64 m = __ballot(bit);
    if (lane == 0) sup[((size_t)n * PREK + i) * 16 + rep * 4 + wv] = m;
  }
}

// ---- K7: sequential greedy NMS + ranked output (one wave per image) --------
__global__ void k_greedy(const float* __restrict__ dsc, const float4* __restrict__ boxes,
                         const u64* __restrict__ sup, float* __restrict__ out) {
  const int n = blockIdx.x;
  const int lane = threadIdx.x;
  const float* d = dsc + n * PREK;
  u64 keep0 = 0;
  for (int w = 0; w < 16; ++w) {
    int i = w * 64 + lane;
    bool b = (i < PREK) && (d[i] > 0.0f);
    u64 m = __ballot(b);
    if (lane == w) keep0 = m;
  }
  const u64* S = sup + (size_t)n * PREK * 16;
  u64 removed = 0;
#define LDR(r) ((lane < 16 && (r) < PREK) ? S[(size_t)(r) * 16 + lane] : 0ULL)
  u64 p0 = LDR(0), p1 = LDR(1), p2 = LDR(2), p3 = LDR(3);
  u64 p4 = LDR(4), p5 = LDR(5), p6 = LDR(6), p7 = LDR(7);
#define STEP(ii, pr) { \
    u64 cur = __shfl(keep0 & ~removed, (ii) >> 6); \
    if ((cur >> ((ii) & 63)) & 1ULL) removed |= pr; \
    pr = LDR((ii) + 8); }
  for (int ib = 0; ib < PREK; ib += 8) {
    STEP(ib + 0, p0) STEP(ib + 1, p1) STEP(ib + 2, p2) STEP(ib + 3, p3)
    STEP(ib + 4, p4) STEP(ib + 5, p5) STEP(ib + 6, p6) STEP(ib + 7, p7)
  }
#undef STEP
#undef LDR
  u64 fk = keep0 & ~removed;
  int base = 0;
  for (int w = 0; w < 16; ++w) {
    u64 m = __shfl(fk, w);
    int i = w * 64 + lane;
    bool kept = (m >> lane) & 1ULL;
    int rank = base + __popcll(m & ((1ULL << lane) - 1ULL));
    if (kept && rank < POSTK && i < PREK) {
      float4 b = boxes[n * PREK + i];
      float* o = out + ((size_t)n * POSTK + rank) * 5;
      o[0] = b.x; o[1] = b.y; o[2] = b.z; o[3] = b.w; o[4] = d[i];
    }
    base += __popcll(m);
  }
}

// ---- launch -----------------------------------------------------------------
extern "C" void kernel_launch(void* const* d_in, const int* in_sizes, int n_in,
                              void* d_out, int out_size, void* d_ws, size_t ws_size,
                              hipStream_t stream) {
  (void)in_sizes; (void)n_in; (void)ws_size;
  const float* cls  = (const float*)d_in[0];
  const float* reg  = (const float*)d_in[1];
  const float* ctr  = (const float*)d_in[2];
  const float* anch = (const float*)d_in[3];
  float* out = (float*)d_out;
  char* ws = (char*)d_ws;

  int*    hist   = (int*)(ws + 0);            // 16*8192*4 = 524288
  int*    selcnt = (int*)(ws + 524288);       // 64
  int*    gB     = (int*)(ws + 524352);       // 64
  int*    gnc    = (int*)(ws + 524416);       // 64
  u64*    sel    = (u64*)(ws + 524480);       // 16*8192*8 = 1048576
  u64*    top    = (u64*)(ws + 1573056);      // 16*1024*8 = 131072
  float4* boxes  = (float4*)(ws + 1704128);   // 16*1000*16 = 256000
  float4* nb     = (float4*)(ws + 1960128);   // 256000
  float*  dsc    = (float*)(ws + 2216128);    // 64000
  u64*    sup    = (u64*)(ws + 2280128);      // 16*1000*16*8 = 2048000 -> end 4328128

  hipMemsetAsync(ws, 0, 524480, stream);                       // hist + counters
  hipMemsetAsync(d_out, 0, (size_t)out_size * sizeof(float), stream);

  dim3 gScan(CHW / 1024, NIMG);               // 2000 x 16, 256 thr, 4 elem/thr
  k_hist   <<<gScan, 256, 0, stream>>>(cls, ctr, hist);
  k_findB  <<<NIMG, 256, 0, stream>>>(hist, gB, gnc);
  k_collect<<<gScan, 256, 0, stream>>>(cls, ctr, gB, selcnt, sel);
  k_sort   <<<NIMG, 1024, 0, stream>>>(selcnt, sel, top);
  k_decode <<<NIMG, 1024, 0, stream>>>(top, gnc, reg, anch, boxes, nb, dsc);
  dim3 gSup(PREK, NIMG);
  k_sup    <<<gSup, 256, 0, stream>>>(nb, dsc, sup);
  k_greedy <<<NIMG, 64, 0, stream>>>(dsc, boxes, sup, out);
}

// Round 3
// 664.351 us; speedup vs baseline: 2.0756x; 2.0756x over previous
//
#include <hip/hip_runtime.h>
#include <stdint.h>

typedef unsigned long long u64;
typedef unsigned int u32;

#define NIMG 16
#define NC 80
#define HW 25600
#define CHW (NC * HW)          // 2,048,000
#define PREK 1000
#define POSTK 200
#define HB2 2048               // coarse bins: float bits >> 19
#define CAPSEL 8192
#define CANDCAP 131072
#define STAGE_CAP 2048
#define EPB 16384              // elements per k_scan block
#define LOGIT_T (-2.9444389791664403f)   // ln(0.05/0.95)
#define SFLOOR 0.05f
#define CLIPDWH 4.135166556742356f        // ln(1000/16)
#define IMGM1 1279.0f
#define OFFMUL 1281.0f
#define NMSTHR 0.8f

// ---- shared candidate evaluation -------------------------------------------
__device__ __forceinline__ bool cand_score(float l, const float* __restrict__ ctrRow,
                                           int e, float& s) {
  if (!(l > LOGIT_T)) return false;             // prob <= 0.05 -> not a candidate
  int loc = e % HW;
  float p  = 1.0f / (1.0f + expf(-l));
  float g  = ctrRow[loc];
  float cg = 1.0f / (1.0f + expf(-g));
  s = p * cg;
  return true;
}

// ---- K1: fused stream: LDS histogram + candidate compaction ----------------
__global__ __launch_bounds__(256) void k_scan(const float* __restrict__ cls,
                                              const float* __restrict__ ctr,
                                              int* __restrict__ hist,
                                              int* __restrict__ gcount,
                                              u64* __restrict__ cand) {
  __shared__ int hh[HB2];                        // 8 KB
  __shared__ u64 stg[STAGE_CAP];                 // 16 KB
  __shared__ int scnt, sbase;
  const int n = blockIdx.y, tid = threadIdx.x;
  for (int i = tid; i < HB2; i += 256) hh[i] = 0;
  if (tid == 0) scnt = 0;
  __syncthreads();
  const float* ctrRow = ctr + (size_t)n * HW;
  const size_t base = (size_t)n * CHW + (size_t)blockIdx.x * EPB;
  for (int it = 0; it < 16; ++it) {
    const int e0 = it * 1024 + tid * 4;
    const float4 v = *reinterpret_cast<const float4*>(cls + base + e0);
    const float L[4] = {v.x, v.y, v.z, v.w};
#pragma unroll
    for (int u = 0; u < 4; ++u) {
      float s;
      int e = blockIdx.x * EPB + e0 + u;         // within-image element id
      if (cand_score(L[u], ctrRow, e, s) && s > SFLOOR) {
        u32 key = __float_as_uint(s) >> 19;      // < 2048 for s < 2
        atomicAdd(&hh[key], 1);                  // LDS atomic (fast)
        int loc = e % HW, c = e / HW;
        u32 idx = (u32)(loc * NC + c);           // reference flat index [HW, C]
        u64 pk = ((u64)__float_as_uint(s) << 32) | (u32)(~idx);
        int pos = atomicAdd(&scnt, 1);
        if (pos < STAGE_CAP) stg[pos] = pk;
        else {                                   // rare spill path
          int gp = atomicAdd(&gcount[n], 1);
          if (gp < CANDCAP) cand[(size_t)n * CANDCAP + gp] = pk;
        }
      }
    }
  }
  __syncthreads();
  // merge nonzero histogram bins (<= ~100 per block at coarse binning)
  for (int i = tid; i < HB2; i += 256) {
    int c = hh[i];
    if (c) atomicAdd(&hist[n * HB2 + i], c);
  }
  // flush staged candidates with a single counter atomic
  if (tid == 0) {
    int c = scnt < STAGE_CAP ? scnt : STAGE_CAP;
    sbase = atomicAdd(&gcount[n], c);
  }
  __syncthreads();
  int c = scnt < STAGE_CAP ? scnt : STAGE_CAP;
  for (int i = tid; i < c; i += 256) {
    int gp = sbase + i;
    if (gp < CANDCAP) cand[(size_t)n * CANDCAP + gp] = stg[i];
  }
}

// ---- K2: find cutoff bin B per image (suffix-scan of 2048-bin hist) --------
__global__ void k_findB(const int* __restrict__ hist, int* __restrict__ gB,
                        int* __restrict__ gnc) {
  __shared__ int ss[256];
  const int n = blockIdx.x, t = threadIdx.x;
  const int* h = hist + n * HB2;
  int s = 0;
#pragma unroll
  for (int b = 0; b < 8; ++b) s += h[t * 8 + b];
  ss[t] = s;
  __syncthreads();
  for (int off = 1; off < 256; off <<= 1) {     // inclusive suffix scan
    int a = (t + off < 256) ? ss[t + off] : 0;
    __syncthreads();
    ss[t] += a;
    __syncthreads();
  }
  int total = ss[0];
  int ncand = total < PREK ? total : PREK;
  if (t == 0) gnc[n] = ncand;
  if (total == 0) { if (t == 0) gB[n] = HB2; return; }     // select nothing
  int Sn = (t < 255) ? ss[t + 1] : 0;
  if (ss[t] >= ncand && Sn < ncand) {           // unique boundary chunk
    int run = Sn, B = t * 8;
    for (int b = t * 8 + 7; b >= t * 8; --b) {
      run += h[b];
      if (run >= ncand) { B = b; break; }
    }
    gB[n] = B;
  }
}

// ---- K3: collect bin >= B from the COMPACTED candidate buffer --------------
__global__ void k_collect(const u64* __restrict__ cand, const int* __restrict__ gcount,
                          const int* __restrict__ gB, int* __restrict__ selcnt,
                          u64* __restrict__ sel) {
  const int n = blockIdx.y;
  const u32 B = (u32)gB[n];
  int cnt = gcount[n]; if (cnt > CANDCAP) cnt = CANDCAP;
  for (int i = blockIdx.x * blockDim.x + threadIdx.x; i < cnt;
       i += gridDim.x * blockDim.x) {
    u64 pk = cand[(size_t)n * CANDCAP + i];
    if ((u32)(pk >> (32 + 19)) >= B) {          // key = score bits >> 19
      int pos = atomicAdd(&selcnt[n], 1);
      if (pos < CAPSEL) sel[(size_t)n * CAPSEL + pos] = pk;
    }
  }
}

// ---- K4: per-image bitonic sort (descending) of selected candidates --------
__global__ __launch_bounds__(1024) void k_sort(const int* __restrict__ selcnt,
                                               const u64* __restrict__ sel,
                                               u64* __restrict__ top) {
  __shared__ u64 a[CAPSEL];                      // 64 KiB
  const int n = blockIdx.x, t = threadIdx.x;
  int cnt = selcnt[n]; if (cnt > CAPSEL) cnt = CAPSEL;
  for (int i = t; i < CAPSEL; i += 1024)
    a[i] = (i < cnt) ? sel[(size_t)n * CAPSEL + i] : 0ULL;
  __syncthreads();
  for (int k = 2; k <= CAPSEL; k <<= 1)
    for (int j = k >> 1; j > 0; j >>= 1) {
      for (int i = t; i < CAPSEL; i += 1024) {
        int ix = i ^ j;
        if (ix > i) {
          u64 x = a[i], y = a[ix];
          bool desc = ((i & k) == 0);
          if (desc ? (x < y) : (x > y)) { a[i] = y; a[ix] = x; }
        }
      }
      __syncthreads();
    }
  top[(size_t)n * 1024 + t] = a[t];
}

// ---- K5: decode boxes, det-scores, offset boxes ----------------------------
__global__ void k_decode(const u64* __restrict__ top, const int* __restrict__ gnc,
                         const float* __restrict__ reg, const float* __restrict__ anch,
                         float4* __restrict__ boxes, float4* __restrict__ nb,
                         float* __restrict__ dsc) {
  const int n = blockIdx.x, k = threadIdx.x;
  if (k >= PREK) return;
  u64 pk = top[(size_t)n * 1024 + k];
  int ncand = gnc[n];
  float4 bx = {0, 0, 0, 0}, nbv = {0, 0, 0, 0};
  float d = 0.0f;
  if (k < ncand && pk != 0ULL) {
    float s = __uint_as_float((u32)(pk >> 32));
    u32 idx = ~(u32)pk;
    int loc = idx / NC, c = idx - loc * NC;
    float r0 = reg[((size_t)n * 4 + 0) * HW + loc];
    float r1 = reg[((size_t)n * 4 + 1) * HW + loc];
    float r2 = reg[((size_t)n * 4 + 2) * HW + loc];
    float r3 = reg[((size_t)n * 4 + 3) * HW + loc];
    float a0 = anch[loc * 4 + 0], a1 = anch[loc * 4 + 1];
    float a2 = anch[loc * 4 + 2], a3 = anch[loc * 4 + 3];
    float w = a2 - a0 + 1.0f, h = a3 - a1 + 1.0f;
    float cx = a0 + 0.5f * w, cy = a1 + 0.5f * h;
    float dx = r0 / 10.0f, dy = r1 / 10.0f;
    float dw = fminf(r2 / 5.0f, CLIPDWH), dh = fminf(r3 / 5.0f, CLIPDWH);
    float pcx = dx * w + cx, pcy = dy * h + cy;
    float pw = expf(dw) * w, ph = expf(dh) * h;
    float x1 = pcx - 0.5f * pw, y1 = pcy - 0.5f * ph;
    float x2 = pcx + 0.5f * pw - 1.0f, y2 = pcy + 0.5f * ph - 1.0f;
    x1 = fminf(fmaxf(x1, 0.0f), IMGM1); y1 = fminf(fmaxf(y1, 0.0f), IMGM1);
    x2 = fminf(fmaxf(x2, 0.0f), IMGM1); y2 = fminf(fmaxf(y2, 0.0f), IMGM1);
    float wsz = x2 - x1 + 1.0f, hsz = y2 - y1 + 1.0f;
    if (wsz >= 0.0f && hsz >= 0.0f) d = sqrtf(s);
    bx = {x1, y1, x2, y2};
    float off = (float)(c + 1) * OFFMUL;        // reference adds offset AFTER clip
    nbv = {x1 + off, y1 + off, x2 + off, y2 + off};
  }
  boxes[n * PREK + k] = bx;
  nb[n * PREK + k] = nbv;
  dsc[n * PREK + k] = d;
}

// ---- K6: suppression bitmask matrix ----------------------------------------
__global__ void k_sup(const float4* __restrict__ nb, const float* __restrict__ dsc,
                      u64* __restrict__ sup) {
  const int i = blockIdx.x, n = blockIdx.y;
  if (dsc[n * PREK + i] == 0.0f) return;        // row never read in greedy phase
  const float4 bi = nb[n * PREK + i];
  const float a1 = fmaxf(bi.z - bi.x, 0.0f) * fmaxf(bi.w - bi.y, 0.0f);
  const int tid = threadIdx.x, lane = tid & 63, wv = tid >> 6;
#pragma unroll
  for (int rep = 0; rep < 4; ++rep) {
    int j = rep * 256 + tid;
    bool bit = false;
    if (j < PREK && j > i) {
      float4 bj = nb[n * PREK + j];
      float xx1 = fmaxf(bi.x, bj.x), yy1 = fmaxf(bi.y, bj.y);
      float xx2 = fminf(bi.z, bj.z), yy2 = fminf(bi.w, bj.w);
      float inter = fmaxf(xx2 - xx1, 0.0f) * fmaxf(yy2 - yy1, 0.0f);
      float a2 = fmaxf(bj.z - bj.x, 0.0f) * fmaxf(bj.w - bj.y, 0.0f);
      float iou = inter / fmaxf(a1 + a2 - inter, 1e-9f);
      bit = iou > NMSTHR;
    }
    u64 m = __ballot(bit);
    if (lane == 0) sup[((size_t)n * PREK + i) * 16 + rep * 4 + wv] = m;
  }
}

// ---- K7: sequential greedy NMS + ranked output (one wave per image) --------
__global__ void k_greedy(const float* __restrict__ dsc, const float4* __restrict__ boxes,
                         const u64* __restrict__ sup, float* __restrict__ out) {
  const int n = blockIdx.x;
  const int lane = threadIdx.x;
  const float* d = dsc + n * PREK;
  u64 keep0 = 0;
  for (int w = 0; w < 16; ++w) {
    int i = w * 64 + lane;
    bool b = (i < PREK) && (d[i] > 0.0f);
    u64 m = __ballot(b);
    if (lane == w) keep0 = m;
  }
  const u64* S = sup + (size_t)n * PREK * 16;
  u64 removed = 0;
#define LDR(r) ((lane < 16 && (r) < PREK) ? S[(size_t)(r) * 16 + lane] : 0ULL)
  u64 p0 = LDR(0), p1 = LDR(1), p2 = LDR(2), p3 = LDR(3);
  u64 p4 = LDR(4), p5 = LDR(5), p6 = LDR(6), p7 = LDR(7);
#define STEP(ii, pr) { \
    u64 cur = __shfl(keep0 & ~removed, (ii) >> 6); \
    if ((cur >> ((ii) & 63)) & 1ULL) removed |= pr; \
    pr = LDR((ii) + 8); }
  for (int ib = 0; ib < PREK; ib += 8) {
    STEP(ib + 0, p0) STEP(ib + 1, p1) STEP(ib + 2, p2) STEP(ib + 3, p3)
    STEP(ib + 4, p4) STEP(ib + 5, p5) STEP(ib + 6, p6) STEP(ib + 7, p7)
  }
#undef STEP
#undef LDR
  u64 fk = keep0 & ~removed;
  int base = 0;
  for (int w = 0; w < 16; ++w) {
    u64 m = __shfl(fk, w);
    int i = w * 64 + lane;
    bool kept = (m >> lane) & 1ULL;
    int rank = base + __popcll(m & ((1ULL << lane) - 1ULL));
    if (kept && rank < POSTK && i < PREK) {
      float4 b = boxes[n * PREK + i];
      float* o = out + ((size_t)n * POSTK + rank) * 5;
      o[0] = b.x; o[1] = b.y; o[2] = b.z; o[3] = b.w; o[4] = d[i];
    }
    base += __popcll(m);
  }
}

// ---- launch -----------------------------------------------------------------
extern "C" void kernel_launch(void* const* d_in, const int* in_sizes, int n_in,
                              void* d_out, int out_size, void* d_ws, size_t ws_size,
                              hipStream_t stream) {
  (void)in_sizes; (void)n_in; (void)ws_size;
  const float* cls  = (const float*)d_in[0];
  const float* reg  = (const float*)d_in[1];
  const float* ctr  = (const float*)d_in[2];
  const float* anch = (const float*)d_in[3];
  float* out = (float*)d_out;
  char* ws = (char*)d_ws;

  int*    hist   = (int*)(ws + 0);             // 16*2048*4 = 131072
  int*    gcount = (int*)(ws + 131072);        // 64
  int*    selcnt = (int*)(ws + 131136);        // 64
  int*    gB     = (int*)(ws + 131200);        // 64
  int*    gnc    = (int*)(ws + 131264);        // 64
  u64*    cand   = (u64*)(ws + 131328);        // 16*131072*8 = 16,777,216
  u64*    sel    = (u64*)(ws + 16908544);      // 16*8192*8 = 1,048,576
  u64*    top    = (u64*)(ws + 17957120);      // 16*1024*8 = 131,072
  float4* boxes  = (float4*)(ws + 18088192);   // 16*1000*16 = 256,000
  float4* nb     = (float4*)(ws + 18344192);   // 256,000
  float*  dsc    = (float*)(ws + 18600192);    // 64,000
  u64*    sup    = (u64*)(ws + 18664192);      // 16*1000*16*8 = 2,048,000 -> end 20,712,192

  hipMemsetAsync(ws, 0, 131328, stream);                       // hist + counters
  hipMemsetAsync(d_out, 0, (size_t)out_size * sizeof(float), stream);

  dim3 gScan(CHW / EPB, NIMG);                 // 125 x 16 blocks
  k_scan   <<<gScan, 256, 0, stream>>>(cls, ctr, hist, gcount, cand);
  k_findB  <<<NIMG, 256, 0, stream>>>(hist, gB, gnc);
  dim3 gCol(32, NIMG);
  k_collect<<<gCol, 256, 0, stream>>>(cand, gcount, gB, selcnt, sel);
  k_sort   <<<NIMG, 1024, 0, stream>>>(selcnt, sel, top);
  k_decode <<<NIMG, 1024, 0, stream>>>(top, gnc, reg, anch, boxes, nb, dsc);
  dim3 gSup(PREK, NIMG);
  k_sup    <<<gSup, 256, 0, stream>>>(nb, dsc, sup);
  k_greedy <<<NIMG, 64, 0, stream>>>(dsc, boxes, sup, out);
}

// Round 4
// 494.994 us; speedup vs baseline: 2.7858x; 1.3421x over previous
//
#include <hip/hip_runtime.h>
#include <stdint.h>

typedef unsigned long long u64;
typedef unsigned int u32;

#define NIMG 16
#define NC 80
#define HW 25600
#define CHW (NC * HW)          // 2,048,000
#define PREK 1000
#define POSTK 200
#define HB2 2048               // coarse bins: float bits >> 19
#define CAPLDS 4096            // LDS sort capacity (selected ~1075 expected)
#define CANDCAP 131072
#define STAGE_CAP 2048
#define EPB 16384              // elements per k_scan block
#define LOGIT_T (-2.9444389791664403f)   // ln(0.05/0.95)
#define SFLOOR 0.05f
#define CLIPDWH 4.135166556742356f        // ln(1000/16)
#define IMGM1 1279.0f
#define OFFMUL 1281.0f
#define NMSTHR 0.8f

// ---- K1: stream 131 MB, compact candidates (s > 0.05), no histogram -------
__global__ __launch_bounds__(256) void k_scan(const float* __restrict__ cls,
                                              const float* __restrict__ ctr,
                                              int* __restrict__ gcount,
                                              u64* __restrict__ cand) {
  __shared__ u64 stg[STAGE_CAP];                 // 16 KB
  __shared__ int scnt, sbase;
  const int n = blockIdx.y, tid = threadIdx.x, lane = tid & 63;
  if (tid == 0) scnt = 0;
  __syncthreads();
  const float* ctrRow = ctr + (size_t)n * HW;
  const size_t base = (size_t)n * CHW + (size_t)blockIdx.x * EPB;
  for (int it = 0; it < 16; ++it) {
    const int e0 = it * 1024 + tid * 4;
    const float4 v = *reinterpret_cast<const float4*>(cls + base + e0);
    const float L[4] = {v.x, v.y, v.z, v.w};
#pragma unroll
    for (int u = 0; u < 4; ++u) {
      const int e = blockIdx.x * EPB + e0 + u;   // within-image element id
      float s = -1.0f;
      bool pass = false;
      u64 pk = 0;
      if (L[u] > LOGIT_T) {                      // prob > 0.05 pre-filter
        float p  = 1.0f / (1.0f + expf(-L[u]));
        int loc = e % HW;
        float cg = 1.0f / (1.0f + expf(-ctrRow[loc]));
        s = p * cg;
        if (s > SFLOOR) {
          int c = e / HW;
          u32 idx = (u32)(loc * NC + c);         // reference flat index [HW, C]
          pk = ((u64)__float_as_uint(s) << 32) | (u32)(~idx);
          pass = true;
        }
      }
      u64 m = __ballot(pass);
      if (m) {                                   // wave-aggregated stage push
        int leader = __ffsll(m) - 1;
        int basew = 0;
        if (lane == leader) basew = atomicAdd(&scnt, __popcll(m));
        basew = __shfl(basew, leader);
        if (pass) {
          int pos = basew + __popcll(m & ((1ULL << lane) - 1ULL));
          if (pos < STAGE_CAP) stg[pos] = pk;
          else {                                 // never expected (690 << 2048)
            int gp = atomicAdd(&gcount[n], 1);
            if (gp < CANDCAP) cand[(size_t)n * CANDCAP + gp] = pk;
          }
        }
      }
    }
  }
  __syncthreads();
  if (tid == 0) {                                // one global atomic per block
    int c = scnt < STAGE_CAP ? scnt : STAGE_CAP;
    sbase = atomicAdd(&gcount[n], c);
  }
  __syncthreads();
  int c = scnt < STAGE_CAP ? scnt : STAGE_CAP;
  for (int i = tid; i < c; i += 256) {
    int gp = sbase + i;
    if (gp < CANDCAP) cand[(size_t)n * CANDCAP + gp] = stg[i];
  }
}

// ---- K2: per-image fused hist -> cutoff -> select -> bitonic sort ----------
__global__ __launch_bounds__(1024) void k_selsort(const u64* __restrict__ cand,
                                                  const int* __restrict__ gcount,
                                                  u64* __restrict__ top,
                                                  int* __restrict__ gnc) {
  __shared__ u64 a[CAPLDS];                      // 32 KB sort arena
  __shared__ int hh[HB2];                        // 8 KB histogram
  __shared__ int ss[1024];                       // 4 KB suffix-scan
  __shared__ int sB, selK;
  const int n = blockIdx.x, t = threadIdx.x, lane = t & 63;
  int cnt = gcount[n]; if (cnt > CANDCAP) cnt = CANDCAP;
  for (int i = t; i < HB2; i += 1024) hh[i] = 0;
  for (int i = t; i < CAPLDS; i += 1024) a[i] = 0ULL;
  if (t == 0) { selK = 0; sB = HB2; }
  __syncthreads();
  const u64* C = cand + (size_t)n * CANDCAP;
  // pass A: LDS histogram of score keys
  for (int i = t; i < cnt; i += 1024)
    atomicAdd(&hh[(u32)(C[i] >> 51)], 1);        // key = score bits >> 19
  __syncthreads();
  ss[t] = hh[2 * t] + hh[2 * t + 1];
  __syncthreads();
  for (int off = 1; off < 1024; off <<= 1) {     // inclusive suffix scan
    int v = (t + off < 1024) ? ss[t + off] : 0;
    __syncthreads();
    ss[t] += v;
    __syncthreads();
  }
  const int total = ss[0];
  const int ncand = total < PREK ? total : PREK;
  if (t == 0) gnc[n] = ncand;
  if (total > 0) {
    int Sn = (t < 1023) ? ss[t + 1] : 0;
    if (ss[t] >= ncand && Sn < ncand) {          // unique boundary chunk of 2
      int run = Sn, B = 2 * t;
      for (int b = 2 * t + 1; b >= 2 * t; --b) {
        run += hh[b];
        if (run >= ncand) { B = b; break; }
      }
      sB = B;
    }
  }
  __syncthreads();
  const u32 B = (u32)sB;
  // pass B: select bin >= B into LDS arena (wave-aggregated LDS counter)
  const int cntR = (cnt + 1023) & ~1023;         // uniform trip count for ballot
  for (int i = t; i < cntR; i += 1024) {
    bool pass = false; u64 pk = 0;
    if (i < cnt) { pk = C[i]; pass = ((u32)(pk >> 51) >= B); }
    u64 m = __ballot(pass);
    if (m) {
      int leader = __ffsll(m) - 1;
      int basew = 0;
      if (lane == leader) basew = atomicAdd(&selK, __popcll(m));
      basew = __shfl(basew, leader);
      if (pass) {
        int pos = basew + __popcll(m & ((1ULL << lane) - 1ULL));
        if (pos < CAPLDS) a[pos] = pk;           // overflow impossible in practice
      }
    }
  }
  __syncthreads();
  // bitonic sort descending (u64 keys; 0 sorts last)
  for (int k = 2; k <= CAPLDS; k <<= 1)
    for (int j = k >> 1; j > 0; j >>= 1) {
      for (int i = t; i < CAPLDS; i += 1024) {
        int ix = i ^ j;
        if (ix > i) {
          u64 x = a[i], y = a[ix];
          bool desc = ((i & k) == 0);
          if (desc ? (x < y) : (x > y)) { a[i] = y; a[ix] = x; }
        }
      }
      __syncthreads();
    }
  if (t < 1024) top[(size_t)n * 1024 + t] = a[t];
}

// ---- K3: decode boxes, det-scores, offset boxes ----------------------------
__global__ void k_decode(const u64* __restrict__ top, const int* __restrict__ gnc,
                         const float* __restrict__ reg, const float* __restrict__ anch,
                         float4* __restrict__ boxes, float4* __restrict__ nb,
                         float* __restrict__ dsc) {
  const int n = blockIdx.x, k = threadIdx.x;
  if (k >= PREK) return;
  u64 pk = top[(size_t)n * 1024 + k];
  int ncand = gnc[n];
  float4 bx = {0, 0, 0, 0}, nbv = {0, 0, 0, 0};
  float d = 0.0f;
  if (k < ncand && pk != 0ULL) {
    float s = __uint_as_float((u32)(pk >> 32));
    u32 idx = ~(u32)pk;
    int loc = idx / NC, c = idx - loc * NC;
    float r0 = reg[((size_t)n * 4 + 0) * HW + loc];
    float r1 = reg[((size_t)n * 4 + 1) * HW + loc];
    float r2 = reg[((size_t)n * 4 + 2) * HW + loc];
    float r3 = reg[((size_t)n * 4 + 3) * HW + loc];
    float a0 = anch[loc * 4 + 0], a1 = anch[loc * 4 + 1];
    float a2 = anch[loc * 4 + 2], a3 = anch[loc * 4 + 3];
    float w = a2 - a0 + 1.0f, h = a3 - a1 + 1.0f;
    float cx = a0 + 0.5f * w, cy = a1 + 0.5f * h;
    float dx = r0 / 10.0f, dy = r1 / 10.0f;
    float dw = fminf(r2 / 5.0f, CLIPDWH), dh = fminf(r3 / 5.0f, CLIPDWH);
    float pcx = dx * w + cx, pcy = dy * h + cy;
    float pw = expf(dw) * w, ph = expf(dh) * h;
    float x1 = pcx - 0.5f * pw, y1 = pcy - 0.5f * ph;
    float x2 = pcx + 0.5f * pw - 1.0f, y2 = pcy + 0.5f * ph - 1.0f;
    x1 = fminf(fmaxf(x1, 0.0f), IMGM1); y1 = fminf(fmaxf(y1, 0.0f), IMGM1);
    x2 = fminf(fmaxf(x2, 0.0f), IMGM1); y2 = fminf(fmaxf(y2, 0.0f), IMGM1);
    float wsz = x2 - x1 + 1.0f, hsz = y2 - y1 + 1.0f;
    if (wsz >= 0.0f && hsz >= 0.0f) d = sqrtf(s);
    bx = {x1, y1, x2, y2};
    float off = (float)(c + 1) * OFFMUL;        // reference adds offset AFTER clip
    nbv = {x1 + off, y1 + off, x2 + off, y2 + off};
  }
  boxes[n * PREK + k] = bx;
  nb[n * PREK + k] = nbv;
  dsc[n * PREK + k] = d;
}

// ---- K4: suppression bitmask matrix ----------------------------------------
__global__ void k_sup(const float4* __restrict__ nb, const float* __restrict__ dsc,
                      u64* __restrict__ sup) {
  const int i = blockIdx.x, n = blockIdx.y;
  if (dsc[n * PREK + i] == 0.0f) return;        // row never read in greedy phase
  const float4 bi = nb[n * PREK + i];
  const float a1 = fmaxf(bi.z - bi.x, 0.0f) * fmaxf(bi.w - bi.y, 0.0f);
  const int tid = threadIdx.x, lane = tid & 63, wv = tid >> 6;
#pragma unroll
  for (int rep = 0; rep < 4; ++rep) {
    int j = rep * 256 + tid;
    bool bit = false;
    if (j < PREK && j > i) {
      float4 bj = nb[n * PREK + j];
      float xx1 = fmaxf(bi.x, bj.x), yy1 = fmaxf(bi.y, bj.y);
      float xx2 = fminf(bi.z, bj.z), yy2 = fminf(bi.w, bj.w);
      float inter = fmaxf(xx2 - xx1, 0.0f) * fmaxf(yy2 - yy1, 0.0f);
      float a2 = fmaxf(bj.z - bj.x, 0.0f) * fmaxf(bj.w - bj.y, 0.0f);
      float iou = inter / fmaxf(a1 + a2 - inter, 1e-9f);
      bit = iou > NMSTHR;
    }
    u64 m = __ballot(bit);
    if (lane == 0) sup[((size_t)n * PREK + i) * 16 + rep * 4 + wv] = m;
  }
}

// ---- K5: sequential greedy NMS + ranked output (one wave per image) --------
__global__ void k_greedy(const float* __restrict__ dsc, const float4* __restrict__ boxes,
                         const u64* __restrict__ sup, float* __restrict__ out) {
  const int n = blockIdx.x;
  const int lane = threadIdx.x;
  const float* d = dsc + n * PREK;
  u64 keep0 = 0;
  for (int w = 0; w < 16; ++w) {
    int i = w * 64 + lane;
    bool b = (i < PREK) && (d[i] > 0.0f);
    u64 m = __ballot(b);
    if (lane == w) keep0 = m;
  }
  const u64* S = sup + (size_t)n * PREK * 16;
  u64 removed = 0;
#define LDR(r) ((lane < 16 && (r) < PREK) ? S[(size_t)(r) * 16 + lane] : 0ULL)
  u64 p0 = LDR(0), p1 = LDR(1), p2 = LDR(2), p3 = LDR(3);
  u64 p4 = LDR(4), p5 = LDR(5), p6 = LDR(6), p7 = LDR(7);
#define STEP(ii, pr) { \
    u64 cur = __shfl(keep0 & ~removed, (ii) >> 6); \
    if ((cur >> ((ii) & 63)) & 1ULL) removed |= pr; \
    pr = LDR((ii) + 8); }
  for (int ib = 0; ib < PREK; ib += 8) {
    STEP(ib + 0, p0) STEP(ib + 1, p1) STEP(ib + 2, p2) STEP(ib + 3, p3)
    STEP(ib + 4, p4) STEP(ib + 5, p5) STEP(ib + 6, p6) STEP(ib + 7, p7)
  }
#undef STEP
#undef LDR
  u64 fk = keep0 & ~removed;
  int base = 0;
  for (int w = 0; w < 16; ++w) {
    u64 m = __shfl(fk, w);
    int i = w * 64 + lane;
    bool kept = (m >> lane) & 1ULL;
    int rank = base + __popcll(m & ((1ULL << lane) - 1ULL));
    if (kept && rank < POSTK && i < PREK) {
      float4 b = boxes[n * PREK + i];
      float* o = out + ((size_t)n * POSTK + rank) * 5;
      o[0] = b.x; o[1] = b.y; o[2] = b.z; o[3] = b.w; o[4] = d[i];
    }
    base += __popcll(m);
  }
}

// ---- launch -----------------------------------------------------------------
extern "C" void kernel_launch(void* const* d_in, const int* in_sizes, int n_in,
                              void* d_out, int out_size, void* d_ws, size_t ws_size,
                              hipStream_t stream) {
  (void)in_sizes; (void)n_in; (void)ws_size;
  const float* cls  = (const float*)d_in[0];
  const float* reg  = (const float*)d_in[1];
  const float* ctr  = (const float*)d_in[2];
  const float* anch = (const float*)d_in[3];
  float* out = (float*)d_out;
  char* ws = (char*)d_ws;

  int*    gcount = (int*)(ws + 0);             // 64
  int*    gnc    = (int*)(ws + 64);            // 64
  u64*    cand   = (u64*)(ws + 128);           // 16*131072*8 = 16,777,216
  u64*    top    = (u64*)(ws + 16777344);      // 16*1024*8 = 131,072
  float4* boxes  = (float4*)(ws + 16908416);   // 16*1000*16 = 256,000
  float4* nb     = (float4*)(ws + 17164416);   // 256,000
  float*  dsc    = (float*)(ws + 17420416);    // 64,000
  u64*    sup    = (u64*)(ws + 17484416);      // 16*1000*16*8 = 2,048,000 -> end 19,532,416

  hipMemsetAsync(ws, 0, 128, stream);                          // gcount (+gnc)
  hipMemsetAsync(d_out, 0, (size_t)out_size * sizeof(float), stream);

  dim3 gScan(CHW / EPB, NIMG);                 // 125 x 16 blocks
  k_scan   <<<gScan, 256, 0, stream>>>(cls, ctr, gcount, cand);
  k_selsort<<<NIMG, 1024, 0, stream>>>(cand, gcount, top, gnc);
  k_decode <<<NIMG, 1024, 0, stream>>>(top, gnc, reg, anch, boxes, nb, dsc);
  dim3 gSup(PREK, NIMG);
  k_sup    <<<gSup, 256, 0, stream>>>(nb, dsc, sup);
  k_greedy <<<NIMG, 64, 0, stream>>>(dsc, boxes, sup, out);
}